// Round 2
// 803.251 us; speedup vs baseline: 1.1862x; 1.1862x over previous
//
#include <hip/hip_runtime.h>

// IcoPool: out[b,f,v] = mean_{k<7} x[b,f,idx[v,k]]
// x: (8, 64, 163842) f32, idx: (40962, 7) int32, out: (8, 64, 40962) f32
//
// v2: the v1 kernel was TA/transaction-bound (464 GB/s = 5.8% HBM, VALU 2.5%):
// 146.8M independent 4B gather lane-loads, each dragging its own cache line.
// Fix: amortize 4 rows per random address.
//   Pass 1 (streaming): xI[g][i] = {x[4g+0][i], x[4g+1][i], x[4g+2][i], x[4g+3][i]}
//   Pass 2 (gather):    one float4 load per (v, k, row-group) -> 36.7M transactions
// Stores go straight to the final (ROWS, V_OUT) layout, lane-coalesced.
// XCD blocking kept: each XCD owns 16 row-groups; v-blocks sweep fastest so the
// active xI slab (2.6 MB/group) stays hot in that XCD's 4 MB L2.
//
// v2.1: use native clang vector type for nontemporal stores (HIP float4 is a
// class type that __builtin_nontemporal_store rejects).

typedef float f4 __attribute__((ext_vector_type(4)));

constexpr int B = 8, F = 64, V_IN = 163842, V_OUT = 40962, K = 7;
constexpr int ROWS = B * F;                        // 512
constexpr int RG   = 4;                            // rows per interleave group
constexpr int NG   = ROWS / RG;                    // 128 groups
constexpr int TPB  = 256;
constexpr int VB   = (V_OUT + TPB - 1) / TPB;      // 161 v-blocks
constexpr int GPX  = NG / 8;                       // 16 groups per XCD
constexpr int GL   = 4;                            // groups per block (pass 2)
constexpr int GSETS = GPX / GL;                    // 4 group-sets per XCD
constexpr int IB1 = (V_IN + TPB - 1) / TPB;        // 641 i-blocks (pass 1)
constexpr size_t XI_BYTES = (size_t)NG * V_IN * sizeof(f4); // 335.5 MB

// ---------------- pass 1: interleave 4 rows into float4 slabs ----------------
__global__ __launch_bounds__(TPB) void icopool_interleave(
    const float* __restrict__ x, f4* __restrict__ xI)
{
    const int g = blockIdx.y;
    const int i = blockIdx.x * TPB + threadIdx.x;
    if (i >= V_IN) return;
    const float* xr = x + (size_t)g * RG * V_IN + i;
    f4 v;
    v.x = xr[0];
    v.y = xr[(size_t)V_IN];
    v.z = xr[(size_t)(2 * V_IN)];
    v.w = xr[(size_t)(3 * V_IN)];
    __builtin_nontemporal_store(v, xI + (size_t)g * V_IN + i);
}

// ---------------- pass 2: gather, 4 rows per random address ----------------
__global__ __launch_bounds__(TPB) void icopool_gather4(
    const f4* __restrict__ xI,
    const int* __restrict__ nidx,
    float*     __restrict__ out)
{
    const int b   = blockIdx.x;
    const int xcd = b & 7;           // HW round-robin XCD assignment
    const int j   = b >> 3;
    const int gs  = j / VB;          // group-set within XCD (slow)
    const int vb  = j % VB;          // v-block (fast -> slab stays hot in L2)
    const int v   = vb * TPB + threadIdx.x;
    if (v >= V_OUT) return;

    const int base = v * K;
    const int i0 = nidx[base + 0];
    const int i1 = nidx[base + 1];
    const int i2 = nidx[base + 2];
    const int i3 = nidx[base + 3];
    const int i4 = nidx[base + 4];
    const int i5 = nidx[base + 5];
    const int i6 = nidx[base + 6];

    const int g0 = xcd * GPX + gs * GL;
    #pragma unroll
    for (int gg = 0; gg < GL; ++gg) {
        const int g = g0 + gg;
        const f4* s = xI + (size_t)g * V_IN;
        const f4 a0 = s[i0];
        const f4 a1 = s[i1];
        const f4 a2 = s[i2];
        const f4 a3 = s[i3];
        const f4 a4 = s[i4];
        const f4 a5 = s[i5];
        const f4 a6 = s[i6];
        const f4 r = (a0 + a1 + a2 + a3 + a4 + a5 + a6) * (1.0f / 7.0f);
        float* o = out + (size_t)(g * RG) * V_OUT + v;
        __builtin_nontemporal_store(r.x, o);
        __builtin_nontemporal_store(r.y, o + (size_t)V_OUT);
        __builtin_nontemporal_store(r.z, o + (size_t)(2 * V_OUT));
        __builtin_nontemporal_store(r.w, o + (size_t)(3 * V_OUT));
    }
}

// ---------------- fallback (v1): direct gather, no workspace ----------------
constexpr int RPB  = 2;
constexpr int RGS  = ROWS / RPB;
constexpr int RG_PER_XCD = RGS / 8;
constexpr int BLOCKS_V1  = RGS * VB;

__global__ __launch_bounds__(TPB) void icopool_gather(
    const float* __restrict__ x,
    const int*   __restrict__ nidx,
    float*       __restrict__ out)
{
    const int b        = blockIdx.x;
    const int xcd      = b & 7;
    const int j        = b >> 3;
    const int rg_local = j / VB;
    const int vb       = j % VB;
    const int rg       = xcd * RG_PER_XCD + rg_local;
    const int r0       = rg * RPB;

    const int v = vb * TPB + threadIdx.x;
    if (v >= V_OUT) return;

    const int base = v * K;
    const int i0 = nidx[base + 0];
    const int i1 = nidx[base + 1];
    const int i2 = nidx[base + 2];
    const int i3 = nidx[base + 3];
    const int i4 = nidx[base + 4];
    const int i5 = nidx[base + 5];
    const int i6 = nidx[base + 6];

    #pragma unroll
    for (int r = 0; r < RPB; ++r) {
        const float* xr = x + (size_t)(r0 + r) * V_IN;
        float s = xr[i0] + xr[i1] + xr[i2] + xr[i3] + xr[i4] + xr[i5] + xr[i6];
        __builtin_nontemporal_store(s * (1.0f / 7.0f),
                                    out + (size_t)(r0 + r) * V_OUT + v);
    }
}

extern "C" void kernel_launch(void* const* d_in, const int* in_sizes, int n_in,
                              void* d_out, int out_size, void* d_ws, size_t ws_size,
                              hipStream_t stream) {
    const float* x    = (const float*)d_in[0];
    const int*   nidx = (const int*)d_in[1];
    float*       out  = (float*)d_out;

    if (ws_size >= XI_BYTES && d_ws != nullptr) {
        f4* xI = (f4*)d_ws;
        icopool_interleave<<<dim3(IB1, NG), dim3(TPB), 0, stream>>>(x, xI);
        icopool_gather4<<<dim3(8 * GSETS * VB), dim3(TPB), 0, stream>>>(xI, nidx, out);
    } else {
        icopool_gather<<<dim3(BLOCKS_V1), dim3(TPB), 0, stream>>>(x, nidx, out);
    }
}

// Round 3
// 711.391 us; speedup vs baseline: 1.3394x; 1.1291x over previous
//
#include <hip/hip_runtime.h>

// IcoPool: out[b,f,v] = mean_{k<7} x[b,f,idx[v,k]]
// x: (8, 64, 163842) f32, idx: (40962, 7) int32, out: (8, 64, 40962) f32
//
// v2: amortize 4 rows per random address via an interleaved copy xI (float4
//     slabs), one dwordx4 gather per (v,k,group). 146.8M -> 36.7M transactions.
// v3: GL 4 -> 1. With GL=4 the live gather window was 4 slabs (10.5 MB) + idx
//     (1.15 MB) > 4 MB per-XCD L2 -> thrash -> FETCH_SIZE 1.03 GB (3x the slab
//     data). With GL=1 the window is 2.62 MB slab + 1.15 MB idx < 4 MB, the
//     vb-fastest sweep keeps one slab hot for 161 consecutive blocks per XCD,
//     and every slab line (avg 7 touches) is fetched from HBM exactly once.

typedef float f4 __attribute__((ext_vector_type(4)));

constexpr int B = 8, F = 64, V_IN = 163842, V_OUT = 40962, K = 7;
constexpr int ROWS = B * F;                        // 512
constexpr int RG   = 4;                            // rows per interleave group
constexpr int NG   = ROWS / RG;                    // 128 groups
constexpr int TPB  = 256;
constexpr int VB   = (V_OUT + TPB - 1) / TPB;      // 161 v-blocks
constexpr int GPX  = NG / 8;                       // 16 groups per XCD
constexpr int IB1 = (V_IN + TPB - 1) / TPB;        // 641 i-blocks (pass 1)
constexpr int BLOCKS2 = 8 * GPX * VB;              // 20608 blocks (pass 2)
constexpr size_t XI_BYTES = (size_t)NG * V_IN * sizeof(f4); // 335.5 MB

// ---------------- pass 1: interleave 4 rows into float4 slabs ----------------
__global__ __launch_bounds__(TPB) void icopool_interleave(
    const float* __restrict__ x, f4* __restrict__ xI)
{
    const int g = blockIdx.y;
    const int i = blockIdx.x * TPB + threadIdx.x;
    if (i >= V_IN) return;
    const float* xr = x + (size_t)g * RG * V_IN + i;
    f4 v;
    v.x = xr[0];
    v.y = xr[(size_t)V_IN];
    v.z = xr[(size_t)(2 * V_IN)];
    v.w = xr[(size_t)(3 * V_IN)];
    __builtin_nontemporal_store(v, xI + (size_t)g * V_IN + i);
}

// ---------------- pass 2: gather, 4 rows per random address ----------------
__global__ __launch_bounds__(TPB) void icopool_gather4(
    const f4* __restrict__ xI,
    const int* __restrict__ nidx,
    float*     __restrict__ out)
{
    const int b   = blockIdx.x;
    const int xcd = b & 7;           // HW round-robin XCD assignment
    const int j   = b >> 3;
    const int gl  = j / VB;          // group within this XCD (slow)
    const int vb  = j % VB;          // v-block (fast -> slab stays hot in L2)
    const int v   = vb * TPB + threadIdx.x;
    if (v >= V_OUT) return;

    const int base = v * K;
    const int i0 = nidx[base + 0];
    const int i1 = nidx[base + 1];
    const int i2 = nidx[base + 2];
    const int i3 = nidx[base + 3];
    const int i4 = nidx[base + 4];
    const int i5 = nidx[base + 5];
    const int i6 = nidx[base + 6];

    const int g = xcd * GPX + gl;
    const f4* s = xI + (size_t)g * V_IN;
    const f4 a0 = s[i0];
    const f4 a1 = s[i1];
    const f4 a2 = s[i2];
    const f4 a3 = s[i3];
    const f4 a4 = s[i4];
    const f4 a5 = s[i5];
    const f4 a6 = s[i6];
    const f4 r = (a0 + a1 + a2 + a3 + a4 + a5 + a6) * (1.0f / 7.0f);
    float* o = out + (size_t)(g * RG) * V_OUT + v;
    __builtin_nontemporal_store(r.x, o);
    __builtin_nontemporal_store(r.y, o + (size_t)V_OUT);
    __builtin_nontemporal_store(r.z, o + (size_t)(2 * V_OUT));
    __builtin_nontemporal_store(r.w, o + (size_t)(3 * V_OUT));
}

// ---------------- fallback (v1): direct gather, no workspace ----------------
constexpr int RPB  = 2;
constexpr int RGS  = ROWS / RPB;
constexpr int RG_PER_XCD = RGS / 8;
constexpr int BLOCKS_V1  = RGS * VB;

__global__ __launch_bounds__(TPB) void icopool_gather(
    const float* __restrict__ x,
    const int*   __restrict__ nidx,
    float*       __restrict__ out)
{
    const int b        = blockIdx.x;
    const int xcd      = b & 7;
    const int j        = b >> 3;
    const int rg_local = j / VB;
    const int vb       = j % VB;
    const int rg       = xcd * RG_PER_XCD + rg_local;
    const int r0       = rg * RPB;

    const int v = vb * TPB + threadIdx.x;
    if (v >= V_OUT) return;

    const int base = v * K;
    const int i0 = nidx[base + 0];
    const int i1 = nidx[base + 1];
    const int i2 = nidx[base + 2];
    const int i3 = nidx[base + 3];
    const int i4 = nidx[base + 4];
    const int i5 = nidx[base + 5];
    const int i6 = nidx[base + 6];

    #pragma unroll
    for (int r = 0; r < RPB; ++r) {
        const float* xr = x + (size_t)(r0 + r) * V_IN;
        float s = xr[i0] + xr[i1] + xr[i2] + xr[i3] + xr[i4] + xr[i5] + xr[i6];
        __builtin_nontemporal_store(s * (1.0f / 7.0f),
                                    out + (size_t)(r0 + r) * V_OUT + v);
    }
}

extern "C" void kernel_launch(void* const* d_in, const int* in_sizes, int n_in,
                              void* d_out, int out_size, void* d_ws, size_t ws_size,
                              hipStream_t stream) {
    const float* x    = (const float*)d_in[0];
    const int*   nidx = (const int*)d_in[1];
    float*       out  = (float*)d_out;

    if (ws_size >= XI_BYTES && d_ws != nullptr) {
        f4* xI = (f4*)d_ws;
        icopool_interleave<<<dim3(IB1, NG), dim3(TPB), 0, stream>>>(x, xI);
        icopool_gather4<<<dim3(BLOCKS2), dim3(TPB), 0, stream>>>(xI, nidx, out);
    } else {
        icopool_gather<<<dim3(BLOCKS_V1), dim3(TPB), 0, stream>>>(x, nidx, out);
    }
}

// Round 4
// 653.889 us; speedup vs baseline: 1.4572x; 1.0879x over previous
//
#include <hip/hip_runtime.h>

// IcoPool: out[b,f,v] = mean_{k<7} x[b,f,idx[v,k]]
// x: (8, 64, 163842) f32, idx: (40962, 7) int32, out: (8, 64, 40962) f32
//
// v2: interleave rows so one random address serves many rows (transaction bound).
// v3: keep gather window < 4 MB per-XCD L2 (FETCH 1.03GB -> 246MB).
// v4: gather pass was MSHR*latency bound: 36.7M private 64B line-fills at
//     ~0.27 fills/cyc/CU (64 MSHRs / ~240cy L2 latency). Fix: RG 4 -> 16.
//     xI entry for vertex i = 64B = rows[0..15]; a 4-lane quad loads it as
//     4x dwordx4 (sub*16) -> coalescer merges to ONE 64B line request.
//     Line-fills drop 4x to 9.17M. Window becomes 10.5MB: > L2 but << 256MB
//     L3, so the extra misses are L3 hits (~+100cy), not HBM (round-2 thrash).

typedef float f4 __attribute__((ext_vector_type(4)));
typedef float f2 __attribute__((ext_vector_type(2)));

constexpr int B = 8, F = 64, V_IN = 163842, V_OUT = 40962, K = 7;
constexpr int ROWS = B * F;                        // 512
constexpr int RG   = 16;                           // rows per interleave group
constexpr int NG   = ROWS / RG;                    // 32 groups
constexpr int TPB  = 256;
constexpr int GPX  = NG / 8;                       // 4 groups per XCD
constexpr int VPB  = TPB / 4;                      // 64 v per block (pass 2)
constexpr int VB   = (V_OUT + VPB - 1) / VPB;      // 641 v-blocks
constexpr int BLOCKS2 = 8 * GPX * VB;              // 20512 blocks
constexpr int I2   = V_IN / 2;                     // 81921 col-pairs (pass 1)
constexpr int IB1  = (I2 + VPB - 1) / VPB;         // 1281 blocks_x (pass 1)
constexpr size_t XI_BYTES = (size_t)NG * V_IN * 64; // 335.5 MB

// ---- pass 1: interleave 16 rows into 64B entries (4 f4 quarters per i) ----
// thread (i2, sub): loads cols {2*i2, 2*i2+1} of rows sub*4..sub*4+3 (f2 loads,
// 8B-aligned everywhere since V_IN*4 % 8 == 0), writes 2 entry-quarters.
__global__ __launch_bounds__(TPB) void icopool_interleave16(
    const float* __restrict__ x, f4* __restrict__ xI)
{
    const int g   = blockIdx.y;
    const int sub = threadIdx.x & 3;
    const int i2  = blockIdx.x * VPB + (threadIdx.x >> 2);
    if (i2 >= I2) return;

    const float* xp = x + (size_t)(g * RG + sub * 4) * V_IN + (size_t)i2 * 2;
    const f2 l0 = *(const f2*)(xp);
    const f2 l1 = *(const f2*)(xp + (size_t)V_IN);
    const f2 l2 = *(const f2*)(xp + 2 * (size_t)V_IN);
    const f2 l3 = *(const f2*)(xp + 3 * (size_t)V_IN);
    const f4 e0 = {l0.x, l1.x, l2.x, l3.x};
    const f4 e1 = {l0.y, l1.y, l2.y, l3.y};
    f4* dst = xI + (size_t)g * V_IN * 4 + (size_t)(i2 * 2) * 4 + sub;
    __builtin_nontemporal_store(e0, dst);
    __builtin_nontemporal_store(e1, dst + 4);
}

// ---- pass 2: gather, quad-cooperative full-line consumption ----
// thread (v, sub): accumulates rows sub*4..sub*4+3. Quad's 4 dwordx4 loads at
// i*64 + sub*16 merge into one 64B line request.
__global__ __launch_bounds__(TPB) void icopool_gather16(
    const f4* __restrict__ xI,
    const int* __restrict__ nidx,
    float*     __restrict__ out)
{
    const int b   = blockIdx.x;
    const int xcd = b & 7;           // HW round-robin XCD assignment
    const int j   = b >> 3;
    const int gl  = j / VB;          // group within this XCD (slow)
    const int vb  = j % VB;          // v-block (fast -> window stays hot)
    const int sub = threadIdx.x & 3;
    const int v   = vb * VPB + (threadIdx.x >> 2);
    if (v >= V_OUT) return;

    const int base = v * K;
    const int i0 = nidx[base + 0];
    const int i1 = nidx[base + 1];
    const int i2 = nidx[base + 2];
    const int i3 = nidx[base + 3];
    const int i4 = nidx[base + 4];
    const int i5 = nidx[base + 5];
    const int i6 = nidx[base + 6];

    const int g = xcd * GPX + gl;
    const f4* s = xI + (size_t)g * V_IN * 4 + sub;
    f4 acc = s[(size_t)i0 * 4];
    acc += s[(size_t)i1 * 4];
    acc += s[(size_t)i2 * 4];
    acc += s[(size_t)i3 * 4];
    acc += s[(size_t)i4 * 4];
    acc += s[(size_t)i5 * 4];
    acc += s[(size_t)i6 * 4];
    acc *= (1.0f / 7.0f);

    float* o = out + (size_t)(g * RG + sub * 4) * V_OUT + v;
    __builtin_nontemporal_store(acc.x, o);
    __builtin_nontemporal_store(acc.y, o + (size_t)V_OUT);
    __builtin_nontemporal_store(acc.z, o + 2 * (size_t)V_OUT);
    __builtin_nontemporal_store(acc.w, o + 3 * (size_t)V_OUT);
}

// ---------------- fallback (v1): direct gather, no workspace ----------------
constexpr int RPB  = 2;
constexpr int RGS  = ROWS / RPB;
constexpr int RG_PER_XCD = RGS / 8;
constexpr int VB1  = (V_OUT + TPB - 1) / TPB;
constexpr int BLOCKS_V1  = RGS * VB1;

__global__ __launch_bounds__(TPB) void icopool_gather(
    const float* __restrict__ x,
    const int*   __restrict__ nidx,
    float*       __restrict__ out)
{
    const int b        = blockIdx.x;
    const int xcd      = b & 7;
    const int j        = b >> 3;
    const int rg_local = j / VB1;
    const int vb       = j % VB1;
    const int rg       = xcd * RG_PER_XCD + rg_local;
    const int r0       = rg * RPB;

    const int v = vb * TPB + threadIdx.x;
    if (v >= V_OUT) return;

    const int base = v * K;
    const int i0 = nidx[base + 0];
    const int i1 = nidx[base + 1];
    const int i2 = nidx[base + 2];
    const int i3 = nidx[base + 3];
    const int i4 = nidx[base + 4];
    const int i5 = nidx[base + 5];
    const int i6 = nidx[base + 6];

    #pragma unroll
    for (int r = 0; r < RPB; ++r) {
        const float* xr = x + (size_t)(r0 + r) * V_IN;
        float s = xr[i0] + xr[i1] + xr[i2] + xr[i3] + xr[i4] + xr[i5] + xr[i6];
        __builtin_nontemporal_store(s * (1.0f / 7.0f),
                                    out + (size_t)(r0 + r) * V_OUT + v);
    }
}

extern "C" void kernel_launch(void* const* d_in, const int* in_sizes, int n_in,
                              void* d_out, int out_size, void* d_ws, size_t ws_size,
                              hipStream_t stream) {
    const float* x    = (const float*)d_in[0];
    const int*   nidx = (const int*)d_in[1];
    float*       out  = (float*)d_out;

    if (ws_size >= XI_BYTES && d_ws != nullptr) {
        f4* xI = (f4*)d_ws;
        icopool_interleave16<<<dim3(IB1, NG), dim3(TPB), 0, stream>>>(x, xI);
        icopool_gather16<<<dim3(BLOCKS2), dim3(TPB), 0, stream>>>(xI, nidx, out);
    } else {
        icopool_gather<<<dim3(BLOCKS_V1), dim3(TPB), 0, stream>>>(x, nidx, out);
    }
}

// Round 5
// 652.525 us; speedup vs baseline: 1.4602x; 1.0021x over previous
//
#include <hip/hip_runtime.h>

// IcoPool: out[b,f,v] = mean_{k<7} x[b,f,idx[v,k]]
// x: (8, 64, 163842) f32, idx: (40962, 7) int32, out: (8, 64, 40962) f32
//
// v2: interleave rows -> one random address serves many rows (txn bound fix).
// v3: keep gather window L2-sized (FETCH 1.03GB -> 246MB).
// v4: RG=16, 64B entries, quad-cooperative full-line gathers (fills 4x down).
// v5: gather was latency/launch bound (0.09 req/cyc/CU vs 0.27 sustainable;
//     20.5k tiny blocks). VPT=4: 28 line-requests in flight per thread,
//     blocks -> 5152. Interleave reads merged only 8B/lane, writes gapped;
//     LDS-transpose tile makes both sides fully coalesced (1KB/wave).

typedef float f4 __attribute__((ext_vector_type(4)));

constexpr int B = 8, F = 64, V_IN = 163842, V_OUT = 40962, K = 7;
constexpr int ROWS = B * F;                        // 512
constexpr int RG   = 16;                           // rows per interleave group
constexpr int NG   = ROWS / RG;                    // 32 groups
constexpr int TPB  = 256;
constexpr int GPX  = NG / 8;                       // 4 groups per XCD
// pass 1
constexpr int CPB  = 256;                          // columns per block
constexpr int IBX  = (V_IN + CPB - 1) / CPB;       // 641
// pass 2
constexpr int VPT  = 4;                            // v per thread
constexpr int VPB2 = 64 * VPT;                     // 256 v per block
constexpr int VB2  = (V_OUT + VPB2 - 1) / VPB2;    // 161
constexpr int BLOCKS2 = 8 * GPX * VB2;             // 5152
constexpr size_t XI_BYTES = (size_t)NG * V_IN * 64; // 335.5 MB

// ---- pass 1: LDS-transpose interleave; both global sides fully coalesced ----
__global__ __launch_bounds__(TPB) void icopool_interleave_lds(
    const float* __restrict__ x, f4* __restrict__ xI)
{
    __shared__ float tile[RG][CPB + 1];
    const int g  = blockIdx.y;
    const int c0 = blockIdx.x * CPB;
    const int t  = threadIdx.x;

    if (c0 + CPB <= V_IN) {
        #pragma unroll
        for (int it = 0; it < 4; ++it) {
            const int r  = it * 4 + (t >> 6);
            const int c4 = (t & 63) * 4;
            const f4 vv = *(const f4*)(x + (size_t)(g * RG + r) * V_IN + c0 + c4);
            tile[r][c4 + 0] = vv.x;
            tile[r][c4 + 1] = vv.y;
            tile[r][c4 + 2] = vv.z;
            tile[r][c4 + 3] = vv.w;
        }
    } else {
        for (int it = 0; it < 4; ++it) {
            const int r  = it * 4 + (t >> 6);
            const int c4 = (t & 63) * 4;
            for (int jj = 0; jj < 4; ++jj) {
                const int c = c0 + c4 + jj;
                tile[r][c4 + jj] = (c < V_IN) ? x[(size_t)(g * RG + r) * V_IN + c] : 0.0f;
            }
        }
    }
    __syncthreads();

    f4* dst = xI + (size_t)g * V_IN * 4;   // f4 units; entry c at dst[c*4 + q]
    #pragma unroll
    for (int it = 0; it < 4; ++it) {
        const int e = it * 64 + (t >> 2);
        const int q = t & 3;
        const int c = c0 + e;
        if (c < V_IN) {
            const f4 vv = { tile[q * 4 + 0][e], tile[q * 4 + 1][e],
                            tile[q * 4 + 2][e], tile[q * 4 + 3][e] };
            __builtin_nontemporal_store(vv, dst + (size_t)c * 4 + q);
        }
    }
}

// ---- pass 2: quad-cooperative gather, VPT v's per thread for deep MLP ----
__global__ __launch_bounds__(TPB) void icopool_gather16v(
    const f4* __restrict__ xI,
    const int* __restrict__ nidx,
    float*     __restrict__ out)
{
    const int b   = blockIdx.x;
    const int xcd = b & 7;               // HW round-robin XCD assignment
    const int j   = b >> 3;
    const int gl  = j / VB2;             // group within XCD (slow)
    const int vb  = j % VB2;             // v-block (fast -> window stays hot)
    const int sub = threadIdx.x & 3;
    const int lv  = threadIdx.x >> 2;    // 0..63
    const int g   = xcd * GPX + gl;
    const f4* s   = xI + (size_t)g * V_IN * 4 + sub;

    #pragma unroll
    for (int i = 0; i < VPT; ++i) {
        const int v = vb * VPB2 + i * 64 + lv;
        if (v < V_OUT) {
            const int base = v * K;
            const int i0 = nidx[base + 0];
            const int i1 = nidx[base + 1];
            const int i2 = nidx[base + 2];
            const int i3 = nidx[base + 3];
            const int i4 = nidx[base + 4];
            const int i5 = nidx[base + 5];
            const int i6 = nidx[base + 6];
            f4 acc = s[(size_t)i0 * 4];
            acc += s[(size_t)i1 * 4];
            acc += s[(size_t)i2 * 4];
            acc += s[(size_t)i3 * 4];
            acc += s[(size_t)i4 * 4];
            acc += s[(size_t)i5 * 4];
            acc += s[(size_t)i6 * 4];
            acc *= (1.0f / 7.0f);
            float* o = out + (size_t)(g * RG + sub * 4) * V_OUT + v;
            __builtin_nontemporal_store(acc.x, o);
            __builtin_nontemporal_store(acc.y, o + (size_t)V_OUT);
            __builtin_nontemporal_store(acc.z, o + 2 * (size_t)V_OUT);
            __builtin_nontemporal_store(acc.w, o + 3 * (size_t)V_OUT);
        }
    }
}

// ---------------- fallback (v1): direct gather, no workspace ----------------
constexpr int RPB  = 2;
constexpr int RGS  = ROWS / RPB;
constexpr int RG_PER_XCD = RGS / 8;
constexpr int VB1  = (V_OUT + TPB - 1) / TPB;
constexpr int BLOCKS_V1  = RGS * VB1;

__global__ __launch_bounds__(TPB) void icopool_gather(
    const float* __restrict__ x,
    const int*   __restrict__ nidx,
    float*       __restrict__ out)
{
    const int b        = blockIdx.x;
    const int xcd      = b & 7;
    const int j        = b >> 3;
    const int rg_local = j / VB1;
    const int vb       = j % VB1;
    const int rg       = xcd * RG_PER_XCD + rg_local;
    const int r0       = rg * RPB;

    const int v = vb * TPB + threadIdx.x;
    if (v >= V_OUT) return;

    const int base = v * K;
    const int i0 = nidx[base + 0];
    const int i1 = nidx[base + 1];
    const int i2 = nidx[base + 2];
    const int i3 = nidx[base + 3];
    const int i4 = nidx[base + 4];
    const int i5 = nidx[base + 5];
    const int i6 = nidx[base + 6];

    #pragma unroll
    for (int r = 0; r < RPB; ++r) {
        const float* xr = x + (size_t)(r0 + r) * V_IN;
        float sum = xr[i0] + xr[i1] + xr[i2] + xr[i3] + xr[i4] + xr[i5] + xr[i6];
        __builtin_nontemporal_store(sum * (1.0f / 7.0f),
                                    out + (size_t)(r0 + r) * V_OUT + v);
    }
}

extern "C" void kernel_launch(void* const* d_in, const int* in_sizes, int n_in,
                              void* d_out, int out_size, void* d_ws, size_t ws_size,
                              hipStream_t stream) {
    const float* x    = (const float*)d_in[0];
    const int*   nidx = (const int*)d_in[1];
    float*       out  = (float*)d_out;

    if (ws_size >= XI_BYTES && d_ws != nullptr) {
        f4* xI = (f4*)d_ws;
        icopool_interleave_lds<<<dim3(IBX, NG), dim3(TPB), 0, stream>>>(x, xI);
        icopool_gather16v<<<dim3(BLOCKS2), dim3(TPB), 0, stream>>>(xI, nidx, out);
    } else {
        icopool_gather<<<dim3(BLOCKS_V1), dim3(TPB), 0, stream>>>(x, nidx, out);
    }
}

// Round 6
// 578.844 us; speedup vs baseline: 1.6461x; 1.1273x over previous
//
#include <hip/hip_runtime.h>

// IcoPool: out[b,f,v] = mean_{k<7} x[b,f,idx[v,k]]
// x: (8, 64, 163842) f32, idx: (40962, 7) int32, out: (8, 64, 40962) f32
//
// v2-v5 history: interleaved slab (one random address serves many rows);
//   L2-window blocking; 64B-entry quad-cooperative gathers; VPT=4 (null).
// v6: pass 2 is fill-bound at rate ~= MSHR/latency (0.27/cyc/CU L2-resident,
//   0.09/cyc/CU L3-resident). Fills = gathered_bytes/64 independent of RG.
//   Only lever left: fewer bytes -> fp16 slab (accumulate in f32).
//   RG=32 rows per 64B entry, NG=16 groups. Pass-2 fills 9.17M -> 4.59M,
//   pass-1 stream 671 -> 503 MB. VPT reverted (proven null).

typedef float    f4 __attribute__((ext_vector_type(4)));
typedef float    f8 __attribute__((ext_vector_type(8)));
typedef _Float16 h8 __attribute__((ext_vector_type(8)));
typedef unsigned int u4 __attribute__((ext_vector_type(4)));

constexpr int B = 8, F = 64, V_IN = 163842, V_OUT = 40962, K = 7;
constexpr int ROWS = B * F;                        // 512
constexpr int RG   = 32;                           // rows per entry (64 B fp16)
constexpr int NG   = ROWS / RG;                    // 16 groups
constexpr int TPB  = 256;
constexpr int GPX  = NG / 8;                       // 2 groups per XCD
// pass 1
constexpr int CPB  = 128;                          // columns per block
constexpr int IBX  = (V_IN + CPB - 1) / CPB;       // 1281
constexpr int LSH  = 34;                           // LDS halves per column (32+pad)
// pass 2
constexpr int VPB  = 64;                           // v per block (4 lanes each)
constexpr int VB   = (V_OUT + VPB - 1) / VPB;      // 641
constexpr int BLOCKS2 = 8 * GPX * VB;              // 10256
constexpr size_t XH_BYTES = (size_t)NG * V_IN * 64; // 167.8 MB

// ---- pass 1: transpose-pack 32 f32 rows -> 64B fp16 entries, via LDS ----
// Phase A: coalesced f4 reads (16B/lane), cvt to fp16, LDS column-major.
// Phase B: 4 dword LDS reads -> one 16B nt-store; wave = 1KB contiguous.
__global__ __launch_bounds__(TPB) void icopool_pack_h(
    const float* __restrict__ x, u4* __restrict__ xH)
{
    __shared__ _Float16 tile[CPB * LSH];           // 8704 B
    const int g  = blockIdx.y;
    const int c0 = blockIdx.x * CPB;
    const int t  = threadIdx.x;
    const int r  = t >> 3;                         // 0..31
    const int ci = t & 7;

    const float* xr = x + (size_t)(g * RG + r) * V_IN;
    if (c0 + CPB <= V_IN) {
        #pragma unroll
        for (int it = 0; it < 4; ++it) {
            const int c4 = ci * 4 + it * 32;
            const f4 vv = *(const f4*)(xr + c0 + c4);
            tile[(c4 + 0) * LSH + r] = (_Float16)vv.x;
            tile[(c4 + 1) * LSH + r] = (_Float16)vv.y;
            tile[(c4 + 2) * LSH + r] = (_Float16)vv.z;
            tile[(c4 + 3) * LSH + r] = (_Float16)vv.w;
        }
    } else {
        for (int it = 0; it < 4; ++it) {
            const int c4 = ci * 4 + it * 32;
            for (int jj = 0; jj < 4; ++jj) {
                const int c = c0 + c4 + jj;
                tile[(c4 + jj) * LSH + r] =
                    (c < V_IN) ? (_Float16)xr[c] : (_Float16)0.0f;
            }
        }
    }
    __syncthreads();

    const unsigned int* ld = (const unsigned int*)tile;  // dword view (17/col)
    u4* dst = xH + ((size_t)g * V_IN + c0) * 4;
    #pragma unroll
    for (int it = 0; it < 2; ++it) {
        const int c   = (t >> 2) + it * 64;        // 0..127
        const int sub = t & 3;
        if (c0 + c < V_IN) {
            u4 w;
            w.x = ld[c * 17 + sub * 4 + 0];
            w.y = ld[c * 17 + sub * 4 + 1];
            w.z = ld[c * 17 + sub * 4 + 2];
            w.w = ld[c * 17 + sub * 4 + 3];
            __builtin_nontemporal_store(w, dst + (size_t)c * 4 + sub);
        }
    }
}

// ---- pass 2: quad-cooperative fp16 gather, f32 accumulate ----
// 4 lanes per v; lane sub loads 16B = rows sub*8..sub*8+7; quad's 4 loads
// merge into ONE 64B line request. Fills = 40962*7*16 = 4.59M.
__global__ __launch_bounds__(TPB) void icopool_gather_h(
    const h8* __restrict__ xH,
    const int* __restrict__ nidx,
    float*     __restrict__ out)
{
    const int b   = blockIdx.x;
    const int xcd = b & 7;               // HW round-robin XCD assignment
    const int j   = b >> 3;
    const int gl  = j / VB;              // group within XCD (slow)
    const int vb  = j % VB;              // v-block (fast -> window stays hot)
    const int sub = threadIdx.x & 3;
    const int lv  = threadIdx.x >> 2;    // 0..63
    const int v   = vb * VPB + lv;
    if (v >= V_OUT) return;
    const int g   = xcd * GPX + gl;

    const int base = v * K;
    const int i0 = nidx[base + 0];
    const int i1 = nidx[base + 1];
    const int i2 = nidx[base + 2];
    const int i3 = nidx[base + 3];
    const int i4 = nidx[base + 4];
    const int i5 = nidx[base + 5];
    const int i6 = nidx[base + 6];

    const h8* s = xH + ((size_t)g * V_IN) * 4 + sub;
    f8 acc = __builtin_convertvector(s[(size_t)i0 * 4], f8);
    acc += __builtin_convertvector(s[(size_t)i1 * 4], f8);
    acc += __builtin_convertvector(s[(size_t)i2 * 4], f8);
    acc += __builtin_convertvector(s[(size_t)i3 * 4], f8);
    acc += __builtin_convertvector(s[(size_t)i4 * 4], f8);
    acc += __builtin_convertvector(s[(size_t)i5 * 4], f8);
    acc += __builtin_convertvector(s[(size_t)i6 * 4], f8);
    acc *= (1.0f / 7.0f);

    float* o = out + (size_t)(g * RG + sub * 8) * V_OUT + v;
    #pragma unroll
    for (int rr = 0; rr < 8; ++rr)
        __builtin_nontemporal_store(acc[rr], o + (size_t)rr * V_OUT);
}

// ---------------- fallback (v1): direct gather, no workspace ----------------
constexpr int RPB  = 2;
constexpr int RGS  = ROWS / RPB;
constexpr int RG_PER_XCD = RGS / 8;
constexpr int VB1  = (V_OUT + TPB - 1) / TPB;
constexpr int BLOCKS_V1  = RGS * VB1;

__global__ __launch_bounds__(TPB) void icopool_gather(
    const float* __restrict__ x,
    const int*   __restrict__ nidx,
    float*       __restrict__ out)
{
    const int b        = blockIdx.x;
    const int xcd      = b & 7;
    const int j        = b >> 3;
    const int rg_local = j / VB1;
    const int vb       = j % VB1;
    const int rg       = xcd * RG_PER_XCD + rg_local;
    const int r0       = rg * RPB;

    const int v = vb * TPB + threadIdx.x;
    if (v >= V_OUT) return;

    const int base = v * K;
    const int i0 = nidx[base + 0];
    const int i1 = nidx[base + 1];
    const int i2 = nidx[base + 2];
    const int i3 = nidx[base + 3];
    const int i4 = nidx[base + 4];
    const int i5 = nidx[base + 5];
    const int i6 = nidx[base + 6];

    #pragma unroll
    for (int r = 0; r < RPB; ++r) {
        const float* xr = x + (size_t)(r0 + r) * V_IN;
        float sum = xr[i0] + xr[i1] + xr[i2] + xr[i3] + xr[i4] + xr[i5] + xr[i6];
        __builtin_nontemporal_store(sum * (1.0f / 7.0f),
                                    out + (size_t)(r0 + r) * V_OUT + v);
    }
}

extern "C" void kernel_launch(void* const* d_in, const int* in_sizes, int n_in,
                              void* d_out, int out_size, void* d_ws, size_t ws_size,
                              hipStream_t stream) {
    const float* x    = (const float*)d_in[0];
    const int*   nidx = (const int*)d_in[1];
    float*       out  = (float*)d_out;

    if (ws_size >= XH_BYTES && d_ws != nullptr) {
        u4* xH = (u4*)d_ws;
        icopool_pack_h<<<dim3(IBX, NG), dim3(TPB), 0, stream>>>(x, xH);
        icopool_gather_h<<<dim3(BLOCKS2), dim3(TPB), 0, stream>>>((const h8*)xH, nidx, out);
    } else {
        icopool_gather<<<dim3(BLOCKS_V1), dim3(TPB), 0, stream>>>(x, nidx, out);
    }
}